// Round 4
// baseline (313.702 us; speedup 1.0000x reference)
//
#include <hip/hip_runtime.h>
#include <hip/hip_bf16.h>
#include <math.h>

#define KNN 5
#define K3 27
#define CENTER 13
#define NCLASSES 21
#define DIM_D 32
#define DIM_H 128
#define DIM_W 2048

// counting-sort buckets: key = (z*H + y)*16 + (x>>7)  -> 32*128*16 = 65536
// leading bits are z -> sorted order is z-major (XCD swizzle exploits this)
#define NBUCKETS 65536
#define SCAN_THREADS 1024
#define CHUNK (NBUCKETS / SCAN_THREADS)   // 64 entries = 16 uint4 per thread

__device__ __forceinline__ unsigned bucket_key(int x, int y, int z) {
    return ((unsigned)(z * DIM_H + y) << 4) | ((unsigned)x >> 7);
}

// 4 points/thread, int4 loads
__global__ __launch_bounds__(256) void hist_kernel(
    const int* __restrict__ px, const int* __restrict__ py,
    const int* __restrict__ pz, unsigned* __restrict__ hist, int P)
{
    int t = blockIdx.x * blockDim.x + threadIdx.x;
    int i0 = t * 4;
    if (i0 + 3 < P) {
        int4 x = ((const int4*)px)[t];
        int4 y = ((const int4*)py)[t];
        int4 z = ((const int4*)pz)[t];
        atomicAdd(&hist[bucket_key(x.x, y.x, z.x)], 1u);
        atomicAdd(&hist[bucket_key(x.y, y.y, z.y)], 1u);
        atomicAdd(&hist[bucket_key(x.z, y.z, z.z)], 1u);
        atomicAdd(&hist[bucket_key(x.w, y.w, z.w)], 1u);
    } else {
        for (int i = i0; i < P; ++i)
            atomicAdd(&hist[bucket_key(px[i], py[i], pz[i])], 1u);
    }
}

// single-block exclusive scan over NBUCKETS, wave-shuffle based (2 barriers)
__global__ __launch_bounds__(SCAN_THREADS) void scan_kernel(unsigned* __restrict__ hist)
{
    __shared__ unsigned wsum[SCAN_THREADS / 64];   // 16 wave totals
    int t = threadIdx.x;
    int lane = t & 63, wid = t >> 6;
    uint4* h4 = (uint4*)hist;
    const size_t base4 = (size_t)t * (CHUNK / 4);

    // pass 1: per-thread sum
    unsigned s = 0;
#pragma unroll
    for (int j = 0; j < CHUNK / 4; ++j) {
        uint4 v = h4[base4 + j];
        s += v.x + v.y + v.z + v.w;
    }
    // wave64 inclusive scan of per-thread sums
    unsigned incl = s;
#pragma unroll
    for (int off = 1; off < 64; off <<= 1) {
        unsigned v = __shfl_up(incl, off);
        if (lane >= off) incl += v;
    }
    if (lane == 63) wsum[wid] = incl;
    __syncthreads();
    if (wid == 0 && lane < SCAN_THREADS / 64) {
        unsigned v = wsum[lane], iv = v;
#pragma unroll
        for (int off = 1; off < SCAN_THREADS / 64; off <<= 1) {
            unsigned u = __shfl_up(iv, off);
            if (lane >= off) iv += u;
        }
        wsum[lane] = iv - v;   // exclusive wave offset
    }
    __syncthreads();
    unsigned run = wsum[wid] + (incl - s);  // thread's exclusive base

    // pass 2: reload + write exclusive prefixes
#pragma unroll
    for (int j = 0; j < CHUNK / 4; ++j) {
        uint4 v = h4[base4 + j];
        uint4 o;
        o.x = run; run += v.x;
        o.y = run; run += v.y;
        o.z = run; run += v.z;
        o.w = run; run += v.w;
        h4[base4 + j] = o;
    }
}

// AoS scatter, 4 points/thread: one aligned 16B store per point
__global__ __launch_bounds__(256) void scatter_aos_kernel(
    const float* __restrict__ ur, const int* __restrict__ px,
    const int* __restrict__ py, const int* __restrict__ pz,
    unsigned* __restrict__ hist, uint4* __restrict__ payload, int P)
{
    int t = blockIdx.x * blockDim.x + threadIdx.x;
    int i0 = t * 4;
    if (i0 + 3 < P) {
        int4 x = ((const int4*)px)[t];
        int4 y = ((const int4*)py)[t];
        int4 z = ((const int4*)pz)[t];
        float4 u = ((const float4*)ur)[t];
        {
            unsigned pos = atomicAdd(&hist[bucket_key(x.x, y.x, z.x)], 1u);
            payload[pos] = make_uint4(__float_as_uint(u.x),
                (unsigned)x.x | ((unsigned)y.x << 11) | ((unsigned)z.x << 18),
                (unsigned)(i0 + 0), 0u);
        }
        {
            unsigned pos = atomicAdd(&hist[bucket_key(x.y, y.y, z.y)], 1u);
            payload[pos] = make_uint4(__float_as_uint(u.y),
                (unsigned)x.y | ((unsigned)y.y << 11) | ((unsigned)z.y << 18),
                (unsigned)(i0 + 1), 0u);
        }
        {
            unsigned pos = atomicAdd(&hist[bucket_key(x.z, y.z, z.z)], 1u);
            payload[pos] = make_uint4(__float_as_uint(u.z),
                (unsigned)x.z | ((unsigned)y.z << 11) | ((unsigned)z.z << 18),
                (unsigned)(i0 + 2), 0u);
        }
        {
            unsigned pos = atomicAdd(&hist[bucket_key(x.w, y.w, z.w)], 1u);
            payload[pos] = make_uint4(__float_as_uint(u.w),
                (unsigned)x.w | ((unsigned)y.w << 11) | ((unsigned)z.w << 18),
                (unsigned)(i0 + 3), 0u);
        }
    } else {
        for (int i = i0; i < P; ++i) {
            int x = px[i], y = py[i], z = pz[i];
            unsigned pos = atomicAdd(&hist[bucket_key(x, y, z)], 1u);
            payload[pos] = make_uint4(__float_as_uint(ur[i]),
                (unsigned)x | ((unsigned)y << 11) | ((unsigned)z << 18),
                (unsigned)i, 0u);
        }
    }
}

__device__ __forceinline__ void bev_knn_body(
    const float* __restrict__ pr, const int* __restrict__ pa,
    float u, int x, int y, int z, int oidx, int* __restrict__ out)
{
    // ---- gather 27 neighbor ranges (clamped addr + select; full MLP) ----
    float dist[K3];
#pragma unroll
    for (int k = 0; k < K3; ++k) {
        const int dz = k / 9 - 1;
        const int dy = (k / 3) % 3 - 1;
        const int dx = k % 3 - 1;
        int zz = z + dz, yy = y + dy, xx = x + dx;
        bool ok = ((unsigned)zz < (unsigned)DIM_D) &
                  ((unsigned)yy < (unsigned)DIM_H) &
                  ((unsigned)xx < (unsigned)DIM_W);
        int zi = ok ? zz : 0;
        int yi = ok ? yy : 0;
        int xi = ok ? xx : 0;
        float r = pr[((size_t)zi * DIM_H + yi) * DIM_W + xi];
        r = ok ? r : 0.0f;              // zero padding
        r = (r < 0.0f) ? INFINITY : r;  // negative-range mask
        float d = fabsf(r - u);
        dist[k] = (k == CENTER) ? 0.0f : d;
    }

    // ---- top-5 smallest, ties -> lower flat index (lax.top_k semantics) ----
    float bd[KNN];
    int   bk[KNN];
#pragma unroll
    for (int j = 0; j < KNN; ++j) { bd[j] = INFINITY; bk[j] = -1; }
#pragma unroll
    for (int k = 0; k < K3; ++k) {
        float dcur = dist[k];
        int   kcur = k;
#pragma unroll
        for (int j = 0; j < KNN; ++j) {
            bool take = dcur < bd[j];
            float td = bd[j]; int tk = bk[j];
            bd[j] = take ? dcur : bd[j];
            bk[j] = take ? kcur : bk[j];
            dcur  = take ? td : dcur;
            kcur  = take ? tk : kcur;
        }
    }

    // ---- gather argmax class only for the 5 winners; apply cutoff ----
    int votes[KNN];
#pragma unroll
    for (int j = 0; j < KNN; ++j) {
        int k = bk[j];
        const int dz = k / 9 - 1;
        const int dy = (k / 3) % 3 - 1;
        const int dx = k % 3 - 1;
        int zz = z + dz, yy = y + dy, xx = x + dx;
        bool ok = ((unsigned)zz < (unsigned)DIM_D) &
                  ((unsigned)yy < (unsigned)DIM_H) &
                  ((unsigned)xx < (unsigned)DIM_W);
        int zi = ok ? zz : 0;
        int yi = ok ? yy : 0;
        int xi = ok ? xx : 0;
        int cls = pa[((size_t)zi * DIM_H + yi) * DIM_W + xi];
        cls = ok ? cls : 0;                       // zero padding -> class 0
        cls = (bd[j] > 1.0f) ? NCLASSES : cls;    // cutoff -> invalid bucket
        votes[j] = cls;
    }

    // ---- majority vote over classes 1..20, ties -> lowest class ----
    int best_cnt = 0, best_cls = 1;  // all-invalid => argmax(zeros)=0 => +1
#pragma unroll
    for (int j = 0; j < KNN; ++j) {
        int v = votes[j];
        if (v >= 1 && v <= NCLASSES - 1) {
            int cnt = 0;
#pragma unroll
            for (int i = 0; i < KNN; ++i) cnt += (votes[i] == v) ? 1 : 0;
            if (cnt > best_cnt || (cnt == best_cnt && v < best_cls)) {
                best_cnt = cnt;
                best_cls = v;
            }
        }
    }
    out[oidx] = best_cls;
}

// XCD-aware swizzle: consecutive sorted chunks stay on one XCD's L2.
__device__ __forceinline__ int swizzle_block(int b, int nb) {
    if ((nb & 7) == 0) {
        int per = nb >> 3;
        return (b & 7) * per + (b >> 3);
    }
    return b;
}

__global__ __launch_bounds__(256) void bev_knn_aos_kernel(
    const float* __restrict__ pr, const int* __restrict__ pa,
    const uint4* __restrict__ payload, int* __restrict__ out, int P)
{
    int lb = swizzle_block(blockIdx.x, gridDim.x);
    int p = lb * blockDim.x + threadIdx.x;
    if (p >= P) return;
    uint4 w = payload[p];
    float u = __uint_as_float(w.x);
    int x = (int)(w.y & 0x7FFu);
    int y = (int)((w.y >> 11) & 0x7Fu);
    int z = (int)((w.y >> 18) & 0x1Fu);
    bev_knn_body(pr, pa, u, x, y, z, (int)w.z, out);
}

__global__ __launch_bounds__(256) void bev_knn_direct_kernel(
    const float* __restrict__ pr, const int* __restrict__ pa,
    const float* __restrict__ ur, const int* __restrict__ px,
    const int* __restrict__ py, const int* __restrict__ pz,
    int* __restrict__ out, int P)
{
    int p = blockIdx.x * blockDim.x + threadIdx.x;
    if (p >= P) return;
    bev_knn_body(pr, pa, ur[p], px[p], py[p], pz[p], p, out);
}

extern "C" void kernel_launch(void* const* d_in, const int* in_sizes, int n_in,
                              void* d_out, int out_size, void* d_ws, size_t ws_size,
                              hipStream_t stream) {
    const float* pr = (const float*)d_in[0];
    const float* ur = (const float*)d_in[1];
    const int*   pa = (const int*)d_in[2];
    const int*   px = (const int*)d_in[3];
    const int*   py = (const int*)d_in[4];
    const int*   pz = (const int*)d_in[5];
    int* out = (int*)d_out;
    int P = in_sizes[1];
    int block = 256;
    int grid = (P + block - 1) / block;
    int grid4 = ((P + 3) / 4 + block - 1) / block;

    size_t hist_b = (size_t)NBUCKETS * 4;
    size_t need_aos = hist_b + (size_t)P * 16;

    if (ws_size >= need_aos) {
        char* ws = (char*)d_ws;
        unsigned* hist    = (unsigned*)ws;
        uint4*    payload = (uint4*)(ws + hist_b);

        hipMemsetAsync(hist, 0, hist_b, stream);
        hist_kernel<<<grid4, block, 0, stream>>>(px, py, pz, hist, P);
        scan_kernel<<<1, SCAN_THREADS, 0, stream>>>(hist);
        scatter_aos_kernel<<<grid4, block, 0, stream>>>(ur, px, py, pz, hist,
                                                        payload, P);
        bev_knn_aos_kernel<<<grid, block, 0, stream>>>(pr, pa, payload, out, P);
    } else {
        bev_knn_direct_kernel<<<grid, block, 0, stream>>>(pr, pa, ur, px, py,
                                                          pz, out, P);
    }
}

// Round 5
// 227.522 us; speedup vs baseline: 1.3788x; 1.3788x over previous
//
#include <hip/hip_runtime.h>
#include <hip/hip_bf16.h>
#include <math.h>

#define KNN 5
#define K3 27
#define CENTER 13
#define NCLASSES 21
#define DIM_D 32
#define DIM_H 128
#define DIM_W 2048

// full sort key (16 bits, z-major): z<<11 | y<<4 | x>>7
// LSD radix: digit0 = key & 0xFF  (y-low:4, x>>7:4)
//            digit1 = key >> 8    (z:5, y-high:3)
// payload w.y = x | y<<11 | z<<18  ->  d0 = (w.y>>7)&0xFF, d1 = (w.y>>15)&0xFF
#define RADIX 256
#define BIN_PTS 2048
#define BIN_THREADS 256

__device__ __forceinline__ unsigned key16(int x, int y, int z) {
    return ((unsigned)z << 11) | ((unsigned)y << 4) | ((unsigned)x >> 7);
}

// ---- pass 0: both digit histograms in one read (order-independent) ----
__global__ __launch_bounds__(256) void hist2_kernel(
    const int* __restrict__ px, const int* __restrict__ py,
    const int* __restrict__ pz, unsigned* __restrict__ h0,
    unsigned* __restrict__ h1, int P)
{
    __shared__ unsigned lh0[RADIX], lh1[RADIX];
    int t = threadIdx.x;
    lh0[t] = 0; lh1[t] = 0;
    __syncthreads();
    int base4 = blockIdx.x * 1024 + t;   // int4 index; block covers 4096 pts
#pragma unroll
    for (int g = 0; g < 4; ++g) {
        int i4 = base4 + g * 256;
        int i0 = i4 * 4;
        if (i0 + 3 < P) {
            int4 X = ((const int4*)px)[i4];
            int4 Y = ((const int4*)py)[i4];
            int4 Z = ((const int4*)pz)[i4];
            unsigned k;
            k = key16(X.x, Y.x, Z.x); atomicAdd(&lh0[k & 0xFF], 1u); atomicAdd(&lh1[k >> 8], 1u);
            k = key16(X.y, Y.y, Z.y); atomicAdd(&lh0[k & 0xFF], 1u); atomicAdd(&lh1[k >> 8], 1u);
            k = key16(X.z, Y.z, Z.z); atomicAdd(&lh0[k & 0xFF], 1u); atomicAdd(&lh1[k >> 8], 1u);
            k = key16(X.w, Y.w, Z.w); atomicAdd(&lh0[k & 0xFF], 1u); atomicAdd(&lh1[k >> 8], 1u);
        } else {
            for (int i = i0; i < P; ++i) {
                unsigned k = key16(px[i], py[i], pz[i]);
                atomicAdd(&lh0[k & 0xFF], 1u);
                atomicAdd(&lh1[k >> 8], 1u);
            }
        }
    }
    __syncthreads();
    if (lh0[t]) atomicAdd(&h0[t], lh0[t]);
    if (lh1[t]) atomicAdd(&h1[t], lh1[t]);
}

// ---- exclusive scan of both 256-entry histograms (single block) ----
__global__ __launch_bounds__(256) void scan2_kernel(
    unsigned* __restrict__ h0, unsigned* __restrict__ h1)
{
    __shared__ unsigned ws0[4], ws1[4];
    int t = threadIdx.x, lane = t & 63, wid = t >> 6;
    unsigned a = h0[t], b = h1[t];
    unsigned ia = a, ib = b;
#pragma unroll
    for (int off = 1; off < 64; off <<= 1) {
        unsigned va = __shfl_up(ia, off);
        unsigned vb = __shfl_up(ib, off);
        if (lane >= off) { ia += va; ib += vb; }
    }
    if (lane == 63) { ws0[wid] = ia; ws1[wid] = ib; }
    __syncthreads();
    unsigned b0 = 0, b1 = 0;
#pragma unroll
    for (int w = 0; w < 4; ++w) {
        b0 += (w < wid) ? ws0[w] : 0u;
        b1 += (w < wid) ? ws1[w] : 0u;
    }
    h0[t] = b0 + ia - a;   // exclusive base -> becomes pass-1 cursor
    h1[t] = b1 + ib - b;   // exclusive base -> becomes pass-2 cursor
}

// ---- shared binning machinery: local hist->rank, scan, chunk-reserve,
//      LDS reorder, semi-coalesced write-out ----
struct BinShared {
    unsigned lh[RADIX];
    unsigned lscan[RADIX];
    unsigned gbase[RADIX];
    unsigned wsum[4];
    uint4 stage[BIN_PTS];   // 32 KB
};

__device__ __forceinline__ void bin_scan_reserve(
    BinShared& S, unsigned* __restrict__ gcur, int t)
{
    int lane = t & 63, wid = t >> 6;
    unsigned c = S.lh[t];
    unsigned inc = c;
#pragma unroll
    for (int off = 1; off < 64; off <<= 1) {
        unsigned v = __shfl_up(inc, off);
        if (lane >= off) inc += v;
    }
    if (lane == 63) S.wsum[wid] = inc;
    __syncthreads();
    unsigned wb = 0;
#pragma unroll
    for (int w = 0; w < 4; ++w) wb += (w < wid) ? S.wsum[w] : 0u;
    S.lscan[t] = wb + inc - c;
    S.gbase[t] = c ? atomicAdd(&gcur[t], c) : 0u;
    __syncthreads();
}

// pass 1: read original SoA arrays, bin by digit0
__global__ __launch_bounds__(BIN_THREADS) void bin_pass1_kernel(
    const float* __restrict__ ur, const int* __restrict__ px,
    const int* __restrict__ py, const int* __restrict__ pz,
    unsigned* __restrict__ g0, uint4* __restrict__ outp, int P)
{
    __shared__ BinShared S;
    int t = threadIdx.x;
    int bstart = blockIdx.x * BIN_PTS;
    int n = min(BIN_PTS, P - bstart);
    S.lh[t] = 0;
    __syncthreads();

    uint4 pay[8];
    unsigned rk[8], dg[8];
#pragma unroll
    for (int g = 0; g < 2; ++g) {
        int i4 = (bstart >> 2) + g * 256 + t;
        int i0 = i4 * 4;
        if (i0 + 3 < P) {
            int4 X = ((const int4*)px)[i4];
            int4 Y = ((const int4*)py)[i4];
            int4 Z = ((const int4*)pz)[i4];
            float4 U = ((const float4*)ur)[i4];
            int xs[4] = {X.x, X.y, X.z, X.w};
            int ys[4] = {Y.x, Y.y, Y.z, Y.w};
            int zs[4] = {Z.x, Z.y, Z.z, Z.w};
            float us[4] = {U.x, U.y, U.z, U.w};
#pragma unroll
            for (int c = 0; c < 4; ++c) {
                int j = g * 4 + c;
                unsigned k = key16(xs[c], ys[c], zs[c]);
                dg[j] = k & 0xFFu;
                rk[j] = atomicAdd(&S.lh[dg[j]], 1u);
                pay[j] = make_uint4(__float_as_uint(us[c]),
                    (unsigned)xs[c] | ((unsigned)ys[c] << 11) | ((unsigned)zs[c] << 18),
                    (unsigned)(i0 + c), 0u);
            }
        } else {
#pragma unroll
            for (int c = 0; c < 4; ++c) {
                int j = g * 4 + c;
                int gi = i0 + c;
                if (gi < P) {
                    int x = px[gi], y = py[gi], z = pz[gi];
                    unsigned k = key16(x, y, z);
                    dg[j] = k & 0xFFu;
                    rk[j] = atomicAdd(&S.lh[dg[j]], 1u);
                    pay[j] = make_uint4(__float_as_uint(ur[gi]),
                        (unsigned)x | ((unsigned)y << 11) | ((unsigned)z << 18),
                        (unsigned)gi, 0u);
                } else {
                    dg[j] = 0xFFFFFFFFu;
                }
            }
        }
    }
    __syncthreads();
    bin_scan_reserve(S, g0, t);
#pragma unroll
    for (int j = 0; j < 8; ++j)
        if (dg[j] != 0xFFFFFFFFu)
            S.stage[S.lscan[dg[j]] + rk[j]] = pay[j];
    __syncthreads();
#pragma unroll
    for (int j = 0; j < 8; ++j) {
        int s = j * 256 + t;
        if (s < n) {
            uint4 v = S.stage[s];
            unsigned d = (v.y >> 7) & 0xFFu;
            unsigned pos = S.gbase[d] + ((unsigned)s - S.lscan[d]);
            outp[pos] = v;
        }
    }
}

// pass 2: read pass-1 payload (coalesced uint4), bin by digit1
__global__ __launch_bounds__(BIN_THREADS) void bin_pass2_kernel(
    const uint4* __restrict__ inp, unsigned* __restrict__ g1,
    uint4* __restrict__ outp, int P)
{
    __shared__ BinShared S;
    int t = threadIdx.x;
    int bstart = blockIdx.x * BIN_PTS;
    int n = min(BIN_PTS, P - bstart);
    S.lh[t] = 0;
    __syncthreads();

    uint4 pay[8];
    unsigned rk[8], dg[8];
#pragma unroll
    for (int j = 0; j < 8; ++j) {
        int i = bstart + j * 256 + t;
        if (i < P) {
            uint4 v = inp[i];
            pay[j] = v;
            dg[j] = (v.y >> 15) & 0xFFu;
            rk[j] = atomicAdd(&S.lh[dg[j]], 1u);
        } else {
            dg[j] = 0xFFFFFFFFu;
        }
    }
    __syncthreads();
    bin_scan_reserve(S, g1, t);
#pragma unroll
    for (int j = 0; j < 8; ++j)
        if (dg[j] != 0xFFFFFFFFu)
            S.stage[S.lscan[dg[j]] + rk[j]] = pay[j];
    __syncthreads();
#pragma unroll
    for (int j = 0; j < 8; ++j) {
        int s = j * 256 + t;
        if (s < n) {
            uint4 v = S.stage[s];
            unsigned d = (v.y >> 15) & 0xFFu;
            unsigned pos = S.gbase[d] + ((unsigned)s - S.lscan[d]);
            outp[pos] = v;
        }
    }
}

// ---- KNN body (unchanged, R1-verified) ----
__device__ __forceinline__ void bev_knn_body(
    const float* __restrict__ pr, const int* __restrict__ pa,
    float u, int x, int y, int z, int oidx, int* __restrict__ out)
{
    float dist[K3];
#pragma unroll
    for (int k = 0; k < K3; ++k) {
        const int dz = k / 9 - 1;
        const int dy = (k / 3) % 3 - 1;
        const int dx = k % 3 - 1;
        int zz = z + dz, yy = y + dy, xx = x + dx;
        bool ok = ((unsigned)zz < (unsigned)DIM_D) &
                  ((unsigned)yy < (unsigned)DIM_H) &
                  ((unsigned)xx < (unsigned)DIM_W);
        int zi = ok ? zz : 0;
        int yi = ok ? yy : 0;
        int xi = ok ? xx : 0;
        float r = pr[((size_t)zi * DIM_H + yi) * DIM_W + xi];
        r = ok ? r : 0.0f;
        r = (r < 0.0f) ? INFINITY : r;
        float d = fabsf(r - u);
        dist[k] = (k == CENTER) ? 0.0f : d;
    }

    float bd[KNN];
    int   bk[KNN];
#pragma unroll
    for (int j = 0; j < KNN; ++j) { bd[j] = INFINITY; bk[j] = -1; }
#pragma unroll
    for (int k = 0; k < K3; ++k) {
        float dcur = dist[k];
        int   kcur = k;
#pragma unroll
        for (int j = 0; j < KNN; ++j) {
            bool take = dcur < bd[j];
            float td = bd[j]; int tk = bk[j];
            bd[j] = take ? dcur : bd[j];
            bk[j] = take ? kcur : bk[j];
            dcur  = take ? td : dcur;
            kcur  = take ? tk : kcur;
        }
    }

    int votes[KNN];
#pragma unroll
    for (int j = 0; j < KNN; ++j) {
        int k = bk[j];
        const int dz = k / 9 - 1;
        const int dy = (k / 3) % 3 - 1;
        const int dx = k % 3 - 1;
        int zz = z + dz, yy = y + dy, xx = x + dx;
        bool ok = ((unsigned)zz < (unsigned)DIM_D) &
                  ((unsigned)yy < (unsigned)DIM_H) &
                  ((unsigned)xx < (unsigned)DIM_W);
        int zi = ok ? zz : 0;
        int yi = ok ? yy : 0;
        int xi = ok ? xx : 0;
        int cls = pa[((size_t)zi * DIM_H + yi) * DIM_W + xi];
        cls = ok ? cls : 0;
        cls = (bd[j] > 1.0f) ? NCLASSES : cls;
        votes[j] = cls;
    }

    int best_cnt = 0, best_cls = 1;
#pragma unroll
    for (int j = 0; j < KNN; ++j) {
        int v = votes[j];
        if (v >= 1 && v <= NCLASSES - 1) {
            int cnt = 0;
#pragma unroll
            for (int i = 0; i < KNN; ++i) cnt += (votes[i] == v) ? 1 : 0;
            if (cnt > best_cnt || (cnt == best_cnt && v < best_cls)) {
                best_cnt = cnt;
                best_cls = v;
            }
        }
    }
    out[oidx] = best_cls;
}

// XCD-aware swizzle: give each XCD a contiguous z-slab of the sorted points
__device__ __forceinline__ int swizzle_block(int b, int nb) {
    if ((nb & 7) == 0) {
        int per = nb >> 3;
        return (b & 7) * per + (b >> 3);
    }
    return b;
}

__global__ __launch_bounds__(256) void bev_knn_aos_kernel(
    const float* __restrict__ pr, const int* __restrict__ pa,
    const uint4* __restrict__ payload, int* __restrict__ out, int P)
{
    int lb = swizzle_block(blockIdx.x, gridDim.x);
    int p = lb * blockDim.x + threadIdx.x;
    if (p >= P) return;
    uint4 w = payload[p];
    float u = __uint_as_float(w.x);
    int x = (int)(w.y & 0x7FFu);
    int y = (int)((w.y >> 11) & 0x7Fu);
    int z = (int)((w.y >> 18) & 0x1Fu);
    bev_knn_body(pr, pa, u, x, y, z, (int)w.z, out);
}

// ---------- fallbacks (smaller ws): R2-proven single scatter ----------
#define NBUCKETS 65536
#define SCAN_THREADS 1024
#define CHUNK (NBUCKETS / SCAN_THREADS)

__device__ __forceinline__ unsigned bucket_key(int x, int y, int z) {
    return ((unsigned)(z * DIM_H + y) << 4) | ((unsigned)x >> 7);
}

__global__ __launch_bounds__(256) void hist_kernel(
    const int* __restrict__ px, const int* __restrict__ py,
    const int* __restrict__ pz, unsigned* __restrict__ hist, int P)
{
    int p = blockIdx.x * blockDim.x + threadIdx.x;
    if (p >= P) return;
    atomicAdd(&hist[bucket_key(px[p], py[p], pz[p])], 1u);
}

__global__ __launch_bounds__(SCAN_THREADS) void scan_kernel(unsigned* __restrict__ hist)
{
    __shared__ unsigned wsum[SCAN_THREADS / 64];
    int t = threadIdx.x;
    int lane = t & 63, wid = t >> 6;
    uint4* h4 = (uint4*)hist;
    const size_t base4 = (size_t)t * (CHUNK / 4);
    unsigned s = 0;
#pragma unroll
    for (int j = 0; j < CHUNK / 4; ++j) {
        uint4 v = h4[base4 + j];
        s += v.x + v.y + v.z + v.w;
    }
    unsigned incl = s;
#pragma unroll
    for (int off = 1; off < 64; off <<= 1) {
        unsigned v = __shfl_up(incl, off);
        if (lane >= off) incl += v;
    }
    if (lane == 63) wsum[wid] = incl;
    __syncthreads();
    if (wid == 0 && lane < SCAN_THREADS / 64) {
        unsigned v = wsum[lane], iv = v;
#pragma unroll
        for (int off = 1; off < SCAN_THREADS / 64; off <<= 1) {
            unsigned u = __shfl_up(iv, off);
            if (lane >= off) iv += u;
        }
        wsum[lane] = iv - v;
    }
    __syncthreads();
    unsigned run = wsum[wid] + (incl - s);
#pragma unroll
    for (int j = 0; j < CHUNK / 4; ++j) {
        uint4 v = h4[base4 + j];
        uint4 o;
        o.x = run; run += v.x;
        o.y = run; run += v.y;
        o.z = run; run += v.z;
        o.w = run; run += v.w;
        h4[base4 + j] = o;
    }
}

__global__ __launch_bounds__(256) void scatter_aos_kernel(
    const float* __restrict__ ur, const int* __restrict__ px,
    const int* __restrict__ py, const int* __restrict__ pz,
    unsigned* __restrict__ hist, uint4* __restrict__ payload, int P)
{
    int p = blockIdx.x * blockDim.x + threadIdx.x;
    if (p >= P) return;
    int x = px[p], y = py[p], z = pz[p];
    unsigned pos = atomicAdd(&hist[bucket_key(x, y, z)], 1u);
    payload[pos] = make_uint4(__float_as_uint(ur[p]),
        (unsigned)x | ((unsigned)y << 11) | ((unsigned)z << 18),
        (unsigned)p, 0u);
}

__global__ __launch_bounds__(256) void bev_knn_direct_kernel(
    const float* __restrict__ pr, const int* __restrict__ pa,
    const float* __restrict__ ur, const int* __restrict__ px,
    const int* __restrict__ py, const int* __restrict__ pz,
    int* __restrict__ out, int P)
{
    int p = blockIdx.x * blockDim.x + threadIdx.x;
    if (p >= P) return;
    bev_knn_body(pr, pa, ur[p], px[p], py[p], pz[p], p, out);
}

extern "C" void kernel_launch(void* const* d_in, const int* in_sizes, int n_in,
                              void* d_out, int out_size, void* d_ws, size_t ws_size,
                              hipStream_t stream) {
    const float* pr = (const float*)d_in[0];
    const float* ur = (const float*)d_in[1];
    const int*   pa = (const int*)d_in[2];
    const int*   px = (const int*)d_in[3];
    const int*   py = (const int*)d_in[4];
    const int*   pz = (const int*)d_in[5];
    int* out = (int*)d_out;
    int P = in_sizes[1];
    int block = 256;
    int grid = (P + block - 1) / block;

    size_t need_radix = 4096 + 2 * (size_t)P * 16;
    size_t need_aos   = (size_t)NBUCKETS * 4 + (size_t)P * 16;

    if (ws_size >= need_radix) {
        char* ws = (char*)d_ws;
        unsigned* h0   = (unsigned*)ws;
        unsigned* h1   = (unsigned*)(ws + 1024);
        uint4*    pay1 = (uint4*)(ws + 4096);
        uint4*    pay2 = (uint4*)(ws + 4096 + (size_t)P * 16);

        int gridH = (P + 4095) / 4096;
        int gridB = (P + BIN_PTS - 1) / BIN_PTS;

        hipMemsetAsync(ws, 0, 4096, stream);
        hist2_kernel<<<gridH, 256, 0, stream>>>(px, py, pz, h0, h1, P);
        scan2_kernel<<<1, 256, 0, stream>>>(h0, h1);
        bin_pass1_kernel<<<gridB, BIN_THREADS, 0, stream>>>(ur, px, py, pz,
                                                            h0, pay1, P);
        bin_pass2_kernel<<<gridB, BIN_THREADS, 0, stream>>>(pay1, h1, pay2, P);
        bev_knn_aos_kernel<<<grid, block, 0, stream>>>(pr, pa, pay2, out, P);
    } else if (ws_size >= need_aos) {
        char* ws = (char*)d_ws;
        unsigned* hist    = (unsigned*)ws;
        uint4*    payload = (uint4*)(ws + (size_t)NBUCKETS * 4);

        hipMemsetAsync(hist, 0, (size_t)NBUCKETS * 4, stream);
        hist_kernel<<<grid, block, 0, stream>>>(px, py, pz, hist, P);
        scan_kernel<<<1, SCAN_THREADS, 0, stream>>>(hist);
        scatter_aos_kernel<<<grid, block, 0, stream>>>(ur, px, py, pz, hist,
                                                       payload, P);
        bev_knn_aos_kernel<<<grid, block, 0, stream>>>(pr, pa, payload, out, P);
    } else {
        bev_knn_direct_kernel<<<grid, block, 0, stream>>>(pr, pa, ur, px, py,
                                                          pz, out, P);
    }
}